// Round 1
// baseline (1653.533 us; speedup 1.0000x reference)
//
#include <hip/hip_runtime.h>
#include <math.h>

#define NA   360
#define VDET 256
#define UDET 256
#define NZ   128
#define NY   128
#define NX   128
#define ZPT  16   // z-slices per thread

// Geometry: dz=dy=dx=2mm, dv=du=2mm, DSO=1000, DSD=1536.
// iv = (z-63.5)*mag + 127.5  in (8.6, 246.4)  -> v never clamps, v1=v0+1 safe.
// iu = yr*mag/2 + 127.5      -> only u needs validity/clamp, uniform over z.

__global__ __launch_bounds__(256) void bp_kernel(const float* __restrict__ proj,
                                                 float* __restrict__ out) {
    __shared__ float2 cs_sh[NA];
    const int tid = threadIdx.y * 128 + threadIdx.x;
    for (int i = tid; i < NA; i += 256) {
        float th = (float)i * (float)(2.0 * M_PI / (double)NA);
        float sv, cv;
        sincosf(th, &sv, &cv);
        cs_sh[i] = make_float2(cv, sv);
    }
    __syncthreads();

    const int x  = threadIdx.x;                  // 0..127
    const int y  = blockIdx.y * 2 + threadIdx.y; // 0..127
    const int zb = blockIdx.x * ZPT;             // z base
    const int b  = blockIdx.z;

    const float xc  = ((float)x - 63.5f) * 2.0f;
    const float yc  = ((float)y - 63.5f) * 2.0f;
    const float zf0 = (float)zb - 63.5f;

    const float* projB = proj + (size_t)b * NA * VDET * UDET;

    float acc[ZPT];
    #pragma unroll
    for (int k = 0; k < ZPT; ++k) acc[k] = 0.0f;

    for (int a = 0; a < NA; ++a) {
        const float2 sc = cs_sh[a];
        const float c = sc.x, s = sc.y;
        const float xr  = xc * c + yc * s;
        const float yr  = yc * c - xc * s;
        const float mag = 1536.0f * __builtin_amdgcn_rcpf(1000.0f - xr);
        const float iu  = fmaf(yr * mag, 0.5f, 127.5f);
        const bool uval = (iu >= 0.0f) && (iu <= 255.0f);
        const float iuc = fminf(fmaxf(iu, 0.0f), 255.0f);
        int u0 = (int)iuc;
        u0 = u0 > (UDET - 2) ? (UDET - 2) : u0;
        const float fu  = iuc - (float)u0;
        const float w   = uval ? 1.0f : 0.0f;
        const float wu1 = fu * w;
        const float wu0 = w - wu1;
        const float* col = projB + a * (VDET * UDET) + u0;
        const float ivb  = fmaf(zf0, mag, 127.5f);
        float kf = 0.0f;
        #pragma unroll
        for (int k = 0; k < ZPT; ++k) {
            const float iv = fmaf(kf, mag, ivb);
            kf += 1.0f;
            const int   v0 = (int)iv;            // iv > 0 -> trunc == floor
            const float fv = iv - (float)v0;
            const float* r = col + (v0 << 8);    // v0 * UDET
            const float p00 = r[0];
            const float p01 = r[1];
            const float p10 = r[UDET];
            const float p11 = r[UDET + 1];
            const float a0 = fmaf(wu1, p01, wu0 * p00);
            const float a1 = fmaf(wu1, p11, wu0 * p10);
            acc[k] += fmaf(fv, a1 - a0, a0);
        }
    }

    float* o = out + (((size_t)b * NZ + zb) * NY + y) * NX + x;
    #pragma unroll
    for (int k = 0; k < ZPT; ++k) {
        o[(size_t)k * (NY * NX)] = acc[k];
    }
}

extern "C" void kernel_launch(void* const* d_in, const int* in_sizes, int n_in,
                              void* d_out, int out_size, void* d_ws, size_t ws_size,
                              hipStream_t stream) {
    const float* proj = (const float*)d_in[0];
    float* out = (float*)d_out;
    dim3 grid(NZ / ZPT, NY / 2, 2);   // (z-groups, y-groups, batch)
    dim3 block(128, 2, 1);
    hipLaunchKernelGGL(bp_kernel, grid, block, 0, stream, proj, out);
}

// Round 2
// 1505.861 us; speedup vs baseline: 1.0981x; 1.0981x over previous
//
#include <hip/hip_runtime.h>
#include <math.h>

#define NA   360
#define VDET 256
#define UDET 256
#define NZ   128
#define NY   128
#define NX   128
#define ZPT  8    // z-slices per thread

// Geometry: dz=dy=dx=2mm, dv=du=2mm, DSO=1000, DSD=1536.
// iv = (zidx-63.5)*mag + 127.5 with |zidx-63.5|<=63.5, mag<=1.872
//   -> iv in (8.6, 246.4): v never clamps, v0+1 always in-bounds.
// iu = yr*mag/2 + 127.5 -> needs validity/clamp; uniform over z, folded
//   into u-weights so the hot loop is branchless and loads stay in-slab.
//
// Wave tiling: lanes = 16x * 4y so each wave-load's detector footprint is
// ~30px x ~3 rows (few cache lines) instead of a 60px x 19-row diagonal.

__global__ __launch_bounds__(256, 8) void bp_kernel(const float* __restrict__ proj,
                                                    float* __restrict__ out) {
    __shared__ float2 cs_sh[NA];
    const int tid = threadIdx.y * 16 + threadIdx.x;
    for (int i = tid; i < NA; i += 256) {
        float th = (float)i * (float)(2.0 * M_PI / (double)NA);
        float sv, cv;
        sincosf(th, &sv, &cv);
        cs_sh[i] = make_float2(cv, sv);
    }
    __syncthreads();

    const int x  = (blockIdx.x & 7) * 16 + threadIdx.x;   // 0..127
    const int y  = (blockIdx.x >> 3) * 16 + threadIdx.y;  // 0..127
    const int zb = blockIdx.y * ZPT;                      // z base
    const int b  = blockIdx.z;

    const float xc  = ((float)x - 63.5f) * 2.0f;
    const float yc  = ((float)y - 63.5f) * 2.0f;
    const float zf0 = (float)zb - 63.5f;

    const float* projB = proj + (size_t)b * NA * VDET * UDET;

    float acc[ZPT];
    #pragma unroll
    for (int k = 0; k < ZPT; ++k) acc[k] = 0.0f;

    for (int a = 0; a < NA; ++a) {
        const float2 sc = cs_sh[a];
        const float c = sc.x, s = sc.y;
        const float xr  = xc * c + yc * s;
        const float yr  = yc * c - xc * s;
        const float mag = 1536.0f * __builtin_amdgcn_rcpf(1000.0f - xr);
        const float iu  = fmaf(yr * mag, 0.5f, 127.5f);
        const bool uval = (iu >= 0.0f) && (iu <= 255.0f);
        const float iuc = fminf(fmaxf(iu, 0.0f), 255.0f);
        int u0 = (int)iuc;
        u0 = u0 > (UDET - 2) ? (UDET - 2) : u0;
        const float fu  = iuc - (float)u0;
        const float w   = uval ? 1.0f : 0.0f;
        const float wu1 = fu * w;
        const float wu0 = w - wu1;
        const float* col = projB + a * (VDET * UDET) + u0;
        const float ivb  = fmaf(zf0, mag, 127.5f);

        // Phase 1: compute coords and issue all gathers (32 loads in flight).
        float fv[ZPT];
        float p00[ZPT], p01[ZPT], p10[ZPT], p11[ZPT];
        #pragma unroll
        for (int k = 0; k < ZPT; ++k) {
            const float iv = fmaf((float)k, mag, ivb);
            const int   v0 = (int)iv;            // iv > 0 -> trunc == floor
            fv[k] = iv - (float)v0;
            const float* r = col + (v0 << 8);    // v0 * UDET
            p00[k] = r[0];
            p01[k] = r[1];
            p10[k] = r[UDET];
            p11[k] = r[UDET + 1];
        }
        // Phase 2: combine.
        #pragma unroll
        for (int k = 0; k < ZPT; ++k) {
            const float a0 = fmaf(wu1, p01[k], wu0 * p00[k]);
            const float a1 = fmaf(wu1, p11[k], wu0 * p10[k]);
            acc[k] += fmaf(fv[k], a1 - a0, a0);
        }
    }

    float* o = out + (((size_t)b * NZ + zb) * NY + y) * NX + x;
    #pragma unroll
    for (int k = 0; k < ZPT; ++k) {
        o[(size_t)k * (NY * NX)] = acc[k];
    }
}

extern "C" void kernel_launch(void* const* d_in, const int* in_sizes, int n_in,
                              void* d_out, int out_size, void* d_ws, size_t ws_size,
                              hipStream_t stream) {
    const float* proj = (const float*)d_in[0];
    float* out = (float*)d_out;
    dim3 grid(64, NZ / ZPT, 2);   // (xy-tiles, z-groups, batch) = 2048 blocks
    dim3 block(16, 16, 1);
    hipLaunchKernelGGL(bp_kernel, grid, block, 0, stream, proj, out);
}

// Round 3
// 1498.753 us; speedup vs baseline: 1.1033x; 1.0047x over previous
//
#include <hip/hip_runtime.h>
#include <math.h>

#define NA   360
#define VDET 256
#define UDET 256
#define NZ   128
#define NY   128
#define NX   128
#define ZPT  8    // z-slices per thread

// Geometry: dz=dy=dx=2mm, dv=du=2mm, DSO=1000, DSD=1536.
// iv = (zidx-63.5)*mag + 127.5 with |zidx-63.5|<=63.5, mag in [1.30,1.88]
//   -> iv in (8.6, 246.4): v never clamps, v0+1 always in-bounds.
// iu = yr*mag/2 + 127.5 -> needs validity/clamp; uniform over z, folded
//   into u-weights so the hot loop is branchless and loads stay in-slab.
//
// R3 change: the two u-taps per row are 8 contiguous bytes -> load as one
// (possibly 4B-aligned) float2. gfx9+ flat/global supports unaligned access;
// this halves vector-memory instructions (the bottleneck per R1->R2 A/B).

__global__ __launch_bounds__(256, 8) void bp_kernel(const float* __restrict__ proj,
                                                    float* __restrict__ out) {
    __shared__ float2 cs_sh[NA];
    const int tid = threadIdx.y * 16 + threadIdx.x;
    for (int i = tid; i < NA; i += 256) {
        float th = (float)i * (float)(2.0 * M_PI / (double)NA);
        float sv, cv;
        sincosf(th, &sv, &cv);
        cs_sh[i] = make_float2(cv, sv);
    }
    __syncthreads();

    const int x  = (blockIdx.x & 7) * 16 + threadIdx.x;   // 0..127
    const int y  = (blockIdx.x >> 3) * 16 + threadIdx.y;  // 0..127
    const int zb = blockIdx.y * ZPT;                      // z base
    const int b  = blockIdx.z;

    const float xc  = ((float)x - 63.5f) * 2.0f;
    const float yc  = ((float)y - 63.5f) * 2.0f;
    const float zf0 = (float)zb - 63.5f;

    const float* projB = proj + (size_t)b * NA * VDET * UDET;

    float acc[ZPT];
    #pragma unroll
    for (int k = 0; k < ZPT; ++k) acc[k] = 0.0f;

    for (int a = 0; a < NA; ++a) {
        const float2 sc = cs_sh[a];
        const float c = sc.x, s = sc.y;
        const float xr  = xc * c + yc * s;
        const float yr  = yc * c - xc * s;
        const float mag = 1536.0f * __builtin_amdgcn_rcpf(1000.0f - xr);
        const float iu  = fmaf(yr * mag, 0.5f, 127.5f);
        const bool uval = (iu >= 0.0f) && (iu <= 255.0f);
        const float iuc = fminf(fmaxf(iu, 0.0f), 255.0f);
        int u0 = (int)iuc;
        u0 = u0 > (UDET - 2) ? (UDET - 2) : u0;
        const float fu  = iuc - (float)u0;
        const float w   = uval ? 1.0f : 0.0f;
        const float wu1 = fu * w;
        const float wu0 = w - wu1;
        const float* col = projB + a * (VDET * UDET) + u0;
        const float ivb  = fmaf(zf0, mag, 127.5f);

        // Phase 1: compute coords and issue all gathers (16 x2-loads in flight).
        float fv[ZPT];
        float2 q0[ZPT], q1[ZPT];
        #pragma unroll
        for (int k = 0; k < ZPT; ++k) {
            const float iv = fmaf((float)k, mag, ivb);
            const int   v0 = (int)iv;            // iv > 0 -> trunc == floor
            fv[k] = iv - (float)v0;
            const float* r = col + (v0 << 8);    // v0 * UDET
            q0[k] = *reinterpret_cast<const float2*>(r);         // u0, u0+1
            q1[k] = *reinterpret_cast<const float2*>(r + UDET);  // row v0+1
        }
        // Phase 2: combine.
        #pragma unroll
        for (int k = 0; k < ZPT; ++k) {
            const float a0 = fmaf(wu1, q0[k].y, wu0 * q0[k].x);
            const float a1 = fmaf(wu1, q1[k].y, wu0 * q1[k].x);
            acc[k] += fmaf(fv[k], a1 - a0, a0);
        }
    }

    float* o = out + (((size_t)b * NZ + zb) * NY + y) * NX + x;
    #pragma unroll
    for (int k = 0; k < ZPT; ++k) {
        o[(size_t)k * (NY * NX)] = acc[k];
    }
}

extern "C" void kernel_launch(void* const* d_in, const int* in_sizes, int n_in,
                              void* d_out, int out_size, void* d_ws, size_t ws_size,
                              hipStream_t stream) {
    const float* proj = (const float*)d_in[0];
    float* out = (float*)d_out;
    dim3 grid(64, NZ / ZPT, 2);   // (xy-tiles, z-groups, batch) = 2048 blocks
    dim3 block(16, 16, 1);
    hipLaunchKernelGGL(bp_kernel, grid, block, 0, stream, proj, out);
}